// Round 5
// baseline (71.958 us; speedup 1.0000x reference)
//
#include <hip/hip_runtime.h>
#include <hip/hip_fp16.h>
#include <math.h>

#define N_NODES 50000
#define F_IN 32
#define DEG 32
#define BATCH 2048
#define NB_STRIDE 100  // ints per staged index row: 96 + 4 pad (bank spread)

typedef _Float16 half8 __attribute__((ext_vector_type(8)));
typedef int int4v __attribute__((ext_vector_type(4)));

__device__ __forceinline__ void softmax3(float a0, float a1, float a2,
                                         float& w0, float& w1, float& w2) {
    float m = fmaxf(a0, fmaxf(a1, a2));
    float e0 = __expf(a0 - m), e1 = __expf(a1 - m), e2 = __expf(a2 - m);
    float s = 1.f / (e0 + e1 + e2);
    w0 = e0 * s; w1 = e1 * s; w2 = e2 * s;
}

__device__ __forceinline__ half8 shfl_xor_h8(half8 x, int m) {
    int4v a = __builtin_bit_cast(int4v, x);
    a.x = __shfl_xor(a.x, m, 64);
    a.y = __shfl_xor(a.y, m, 64);
    a.z = __shfl_xor(a.z, m, 64);
    a.w = __shfl_xor(a.w, m, 64);
    return __builtin_bit_cast(half8, a);
}

// ---- Kernel A: h0 = relu(feat @ w_mlp + b) -> fp16, grid-strided.
// Block 0 also builds softmax(alpha1/alpha2) tables in ws.
__global__ __launch_bounds__(256) void mlp_kernel(
        const float* __restrict__ feat,
        const float* __restrict__ w,
        const float* __restrict__ b,
        const float* __restrict__ alpha1,
        const float* __restrict__ alpha2,
        float* __restrict__ sw1,    // 128*3
        float* __restrict__ sw2,    // 256*3
        _Float16* __restrict__ h0) {
    __shared__ float wl[F_IN * 64];
    __shared__ float fl[2][4 * F_IN];
    int tid = threadIdx.x;
    if (blockIdx.x == 0) {
        for (int q = tid; q < 384; q += 256) {
            const float* src = (q < 128) ? (alpha1 + q * 3) : (alpha2 + (q - 128) * 3);
            float* dst = (q < 128) ? (sw1 + q * 3) : (sw2 + (q - 128) * 3);
            float w0, w1, w2;
            softmax3(src[0], src[1], src[2], w0, w1, w2);
            dst[0] = w0; dst[1] = w1; dst[2] = w2;
        }
    }
    for (int i = tid; i < F_IN * 64; i += 256) wl[i] = w[i];
    int local = tid >> 6;
    int j = tid & 63;
    float bj = b[j];
    int buf = 0;
    const int nquads = N_NODES / 4;  // 12500
    for (int q = blockIdx.x; q < nquads; q += gridDim.x) {
        if (tid < 4 * F_IN)
            fl[buf][tid] = __builtin_nontemporal_load(feat + (size_t)q * 4 * F_IN + tid);
        __syncthreads();
        float acc = bj;
#pragma unroll
        for (int k = 0; k < F_IN; ++k) acc += fl[buf][local * F_IN + k] * wl[k * 64 + j];
        h0[(size_t)(q * 4 + local) * 64 + j] = (_Float16)fmaxf(acc, 0.f);
        buf ^= 1;
    }
}

// ---- Kernel B: layer-1 InterAgg, 8 nodes per wave (32/block), no shuffles.
// Lane j: node m = (wave*8)+(j>>3), feature octet e = j&7. Each lane serially
// accumulates its node's 96 neighbor rows (octet slice). adj staged nt;
// inter1 stored nt so h0 keeps the L2.
__global__ __launch_bounds__(256) void layer1_kernel(
        const int* __restrict__ adj,
        const _Float16* __restrict__ h0,
        const float* __restrict__ sw1,
        _Float16* __restrict__ out) {
    __shared__ int nb[32 * NB_STRIDE];  // 12.5 KB
    __shared__ float swl[384];          // wA(192) | wB(192)
    int tid = threadIdx.x;
    int n0 = blockIdx.x * 32;
    if (tid < 96)
        reinterpret_cast<float4*>(swl)[tid] = reinterpret_cast<const float4*>(sw1)[tid];
    // stage adj: 3 relations x 32 nodes x 32 deg, int4-coalesced, non-temporal
    {
        int i0 = tid * 4;          // int index within a 1024-int relation block
        int m = i0 >> 5;           // node local 0..31
        int d = i0 & 31;
        int gn = n0 + m;
#pragma unroll
        for (int r = 0; r < 3; ++r) {
            int4v v = {0, 0, 0, 0};
            if (gn < N_NODES)
                v = __builtin_nontemporal_load(reinterpret_cast<const int4v*>(
                        adj + ((size_t)r * N_NODES + gn) * DEG + d));
            *reinterpret_cast<int4v*>(&nb[m * NB_STRIDE + r * 32 + d]) = v;
        }
    }
    __syncthreads();
    int w = tid >> 6, j = tid & 63;
    int m = w * 8 + (j >> 3);
    int e = j & 7;
    int n = n0 + m;
    const int* nbrow = nb + m * NB_STRIDE;
    const char* hb = (const char*)h0 + 16 * e;  // octet base
    half8 acc0 = {}, acc1 = {}, acc2 = {};
#pragma unroll 8
    for (int t = 0; t < 32; ++t)
        acc0 += *reinterpret_cast<const half8*>(hb + (size_t)((unsigned)nbrow[t] * 128u));
#pragma unroll 8
    for (int t = 32; t < 64; ++t)
        acc1 += *reinterpret_cast<const half8*>(hb + (size_t)((unsigned)nbrow[t] * 128u));
#pragma unroll 8
    for (int t = 64; t < 96; ++t)
        acc2 += *reinterpret_cast<const half8*>(hb + (size_t)((unsigned)nbrow[t] * 128u));

    half8 sv = *reinterpret_cast<const half8*>(hb + (size_t)((unsigned)n * 128u));
    float wA[24], wB[24];
    {
        const float4* pa = reinterpret_cast<const float4*>(swl + 24 * e);
        const float4* pb = reinterpret_cast<const float4*>(swl + 192 + 24 * e);
#pragma unroll
        for (int q = 0; q < 6; ++q) {
            float4 ta = pa[q], tb = pb[q];
            wA[4 * q] = ta.x; wA[4 * q + 1] = ta.y; wA[4 * q + 2] = ta.z; wA[4 * q + 3] = ta.w;
            wB[4 * q] = tb.x; wB[4 * q + 1] = tb.y; wB[4 * q + 2] = tb.z; wB[4 * q + 3] = tb.w;
        }
    }
    const float inv = 1.f / 32.f;
    half8 ra, rb;
#pragma unroll
    for (int i = 0; i < 8; ++i) {
        float a0 = (float)acc0[i] * inv, a1 = (float)acc1[i] * inv, a2 = (float)acc2[i] * inv;
        float s = (float)sv[i];
        ra[i] = (_Float16)(wA[3 * i] * a0 + wA[3 * i + 1] * a1 + wA[3 * i + 2] * a2);
        rb[i] = (_Float16)(wB[3 * i] * (s - a0) + wB[3 * i + 1] * (s - a1) +
                           wB[3 * i + 2] * (s - a2));
    }
    if (n < N_NODES) {
        __builtin_nontemporal_store(__builtin_bit_cast(int4v, ra),
            reinterpret_cast<int4v*>(out + (size_t)n * 128 + 8 * e));
        __builtin_nontemporal_store(__builtin_bit_cast(int4v, rb),
            reinterpret_cast<int4v*>(out + (size_t)n * 128 + 64 + 8 * e));
    }
}

// ---- Kernel C: layer-2 InterAgg (batch) + fused dense head, packed math.
// 4 batch nodes/block, one wave per node. g=j>>4 (4 rows/instr), e=j&15.
__global__ __launch_bounds__(256) void layer2_kernel(
        const int* __restrict__ nodes,
        const int* __restrict__ adj,
        const _Float16* __restrict__ h0,
        const _Float16* __restrict__ i1,
        const float* __restrict__ sw2,
        const float* __restrict__ w_d2,
        const float* __restrict__ b_d2,
        const float* __restrict__ w_d1,
        const float* __restrict__ b_d1,
        const float* __restrict__ prior,
        float* __restrict__ out) {
    __shared__ int nb[4][96];
    __shared__ int nid[4];
    __shared__ float swl[768];  // wA(384) | wB(384)
    int tid = threadIdx.x;
    int b0 = blockIdx.x * 4;
    if (tid < 4) nid[tid] = nodes[b0 + tid];
    if (tid >= 64 && tid < 256) {
        int q = tid - 64;  // 192 float4 = 768 floats
        reinterpret_cast<float4*>(swl)[q] = reinterpret_cast<const float4*>(sw2)[q];
    }
    __syncthreads();
    for (int q = tid; q < 384; q += 256) {
        int local = q / 96, idx = q - local * 96;
        int r = idx >> 5, d = idx & 31;
        nb[local][idx] = __builtin_nontemporal_load(
            adj + ((size_t)r * N_NODES + nid[local]) * DEG + d);
    }
    __syncthreads();
    int local = tid >> 6, j = tid & 63;
    int bb = b0 + local;
    int n = nid[local];
    int g = j >> 4, e = j & 15;
    int idxs[24];
#pragma unroll
    for (int t = 0; t < 24; ++t) idxs[t] = nb[local][t * 4 + g];
    half8 acc0 = {}, acc1 = {}, acc2 = {};
#pragma unroll
    for (int t = 0; t < 8; ++t)
        acc0 += *reinterpret_cast<const half8*>(i1 + (size_t)idxs[t] * 128 + 8 * e);
#pragma unroll
    for (int t = 8; t < 16; ++t)
        acc1 += *reinterpret_cast<const half8*>(i1 + (size_t)idxs[t] * 128 + 8 * e);
#pragma unroll
    for (int t = 16; t < 24; ++t)
        acc2 += *reinterpret_cast<const half8*>(i1 + (size_t)idxs[t] * 128 + 8 * e);
#pragma unroll
    for (int m = 16; m <= 32; m <<= 1) {
        acc0 += shfl_xor_h8(acc0, m);
        acc1 += shfl_xor_h8(acc1, m);
        acc2 += shfl_xor_h8(acc2, m);
    }
    const float inv = 1.f / 32.f;
    float p0 = 0.f, p1 = 0.f;
    if (g == 0) {
        // inter2 contribution for features f=8e..8e+7
        half8 sv = *reinterpret_cast<const half8*>(i1 + (size_t)n * 128 + 8 * e);
        const float* wa = swl + 24 * e;
        const float* wb = swl + 384 + 24 * e;
#pragma unroll
        for (int i = 0; i < 8; ++i) {
            int f = 8 * e + i;
            float a0 = (float)acc0[i] * inv, a1 = (float)acc1[i] * inv,
                  a2 = (float)acc2[i] * inv;
            float s = (float)sv[i];
            float i2a = wa[3 * i] * a0 + wa[3 * i + 1] * a1 + wa[3 * i + 2] * a2;
            float i2b = wb[3 * i] * (s - a0) + wb[3 * i + 1] * (s - a1) +
                        wb[3 * i + 2] * (s - a2);
            p0 += i2a * w_d2[(192 + f) * 2 + 0] + i2b * w_d2[(320 + f) * 2 + 0];
            p1 += i2a * w_d2[(192 + f) * 2 + 1] + i2b * w_d2[(320 + f) * 2 + 1];
        }
    } else if (g == 1) {
        // self h0 features 4e..4e+3
#pragma unroll
        for (int i = 0; i < 4; ++i) {
            int f = 4 * e + i;
            float s = (float)h0[(size_t)n * 64 + f];
            p0 += s * w_d2[f * 2 + 0];
            p1 += s * w_d2[f * 2 + 1];
        }
    } else if (g == 2) {
        // self inter1 features 8e..8e+7 -> w_d2 rows 64+f
        half8 sv = *reinterpret_cast<const half8*>(i1 + (size_t)n * 128 + 8 * e);
#pragma unroll
        for (int i = 0; i < 8; ++i) {
            int f = 8 * e + i;
            float s = (float)sv[i];
            p0 += s * w_d2[(64 + f) * 2 + 0];
            p1 += s * w_d2[(64 + f) * 2 + 1];
        }
    }
#pragma unroll
    for (int m = 1; m <= 32; m <<= 1) {
        p0 += __shfl_xor(p0, m, 64);
        p1 += __shfl_xor(p1, m, 64);
    }
    if (j == 0) {
        float x0 = p0 + b_d2[0], x1 = p1 + b_d2[1];
        x0 = x0 > 0.f ? x0 : 0.3f * x0;
        x1 = x1 > 0.f ? x1 : 0.3f * x1;
        x0 += __logf(prior[0]);
        x1 += __logf(prior[1]);
        float z = x0 * w_d1[0] + x1 * w_d1[1] + b_d1[0];
        out[bb] = 1.f / (1.f + __expf(-z));
    }
}

extern "C" void kernel_launch(void* const* d_in, const int* in_sizes, int n_in,
                              void* d_out, int out_size, void* d_ws, size_t ws_size,
                              hipStream_t stream) {
    const int*   nodes  = (const int*)d_in[0];
    const float* feat   = (const float*)d_in[1];
    const int*   adj    = (const int*)d_in[2];
    const float* prior  = (const float*)d_in[3];
    const float* w_mlp  = (const float*)d_in[4];
    const float* b_mlp  = (const float*)d_in[5];
    const float* alpha1 = (const float*)d_in[6];
    const float* alpha2 = (const float*)d_in[7];
    const float* w_d2   = (const float*)d_in[8];
    const float* b_d2   = (const float*)d_in[9];
    const float* w_d1   = (const float*)d_in[10];
    const float* b_d1   = (const float*)d_in[11];
    float* out = (float*)d_out;

    // ws layout: sw1 (128*3 f32) | sw2 (256*3 f32) | pad to 8192B |
    //            h0 fp16 (N*64)  | inter1 fp16 (N*128)
    float* sw1 = (float*)d_ws;
    float* sw2 = sw1 + 128 * 3;
    _Float16* h0f = (_Float16*)((char*)d_ws + 8192);
    _Float16* i1f = h0f + (size_t)N_NODES * 64;

    mlp_kernel<<<2048, 256, 0, stream>>>(feat, w_mlp, b_mlp, alpha1, alpha2,
                                         sw1, sw2, h0f);
    layer1_kernel<<<(N_NODES + 31) / 32, 256, 0, stream>>>(adj, h0f, sw1, i1f);
    layer2_kernel<<<BATCH / 4, 256, 0, stream>>>(nodes, adj, h0f, i1f, sw2,
                                                 w_d2, b_d2, w_d1, b_d1, prior, out);
}

// Round 6
// 59.057 us; speedup vs baseline: 1.2185x; 1.2185x over previous
//
#include <hip/hip_runtime.h>
#include <hip/hip_fp16.h>
#include <math.h>

#define N_NODES 50000
#define F_IN 32
#define DEG 32
#define BATCH 2048
#define NB_STRIDE 100  // ints per staged index row: 96 + 4 pad

typedef _Float16 half8 __attribute__((ext_vector_type(8)));
typedef _Float16 half2v __attribute__((ext_vector_type(2)));
typedef int int4v __attribute__((ext_vector_type(4)));
typedef unsigned int uint2v __attribute__((ext_vector_type(2)));
typedef float f32x2 __attribute__((ext_vector_type(2)));

__device__ __forceinline__ void softmax3(float a0, float a1, float a2,
                                         float& w0, float& w1, float& w2) {
    float m = fmaxf(a0, fmaxf(a1, a2));
    float e0 = __expf(a0 - m), e1 = __expf(a1 - m), e2 = __expf(a2 - m);
    float s = 1.f / (e0 + e1 + e2);
    w0 = e0 * s; w1 = e1 * s; w2 = e2 * s;
}

__device__ __forceinline__ f32x2 shfl_xor_f2(f32x2 v, int m) {
    v.x = __shfl_xor(v.x, m, 64);
    v.y = __shfl_xor(v.y, m, 64);
    return v;
}

// ---- Kernel A: h0 = relu(feat @ w_mlp + b) -> fp16 master + fp8 gather copy.
// 8 nodes / 256-thread block, 2 features per thread. Grid-strided.
__global__ __launch_bounds__(256) void mlp_kernel(
        const float* __restrict__ feat,
        const float* __restrict__ w,
        const float* __restrict__ b,
        const float* __restrict__ alpha1,
        const float* __restrict__ alpha2,
        float* __restrict__ sw1,    // 128*3
        float* __restrict__ sw2,    // 256*3
        _Float16* __restrict__ h0h,
        unsigned char* __restrict__ h0q) {
    __shared__ float wl[F_IN * 64];
    __shared__ float fl[8 * F_IN];
    int tid = threadIdx.x;
    if (blockIdx.x == 0) {
        for (int q = tid; q < 384; q += 256) {
            const float* src = (q < 128) ? (alpha1 + q * 3) : (alpha2 + (q - 128) * 3);
            float* dst = (q < 128) ? (sw1 + q * 3) : (sw2 + (q - 128) * 3);
            float w0, w1, w2;
            softmax3(src[0], src[1], src[2], w0, w1, w2);
            dst[0] = w0; dst[1] = w1; dst[2] = w2;
        }
    }
    for (int i = tid; i < F_IN * 64; i += 256) wl[i] = w[i];
    int local = tid >> 5;        // node 0..7
    int f2 = (tid & 31) * 2;     // feature pair
    float b0 = b[f2], b1 = b[f2 + 1];
    const int noct = N_NODES / 8;  // 6250
    for (int q = blockIdx.x; q < noct; q += gridDim.x) {
        int n0 = q * 8;
        __syncthreads();  // protect fl from previous iteration's readers
        fl[tid] = __builtin_nontemporal_load(feat + (size_t)n0 * F_IN + tid);
        __syncthreads();
        float a0 = b0, a1 = b1;
#pragma unroll
        for (int k = 0; k < F_IN; ++k) {
            float v = fl[local * F_IN + k];
            a0 = fmaf(v, wl[k * 64 + f2], a0);
            a1 = fmaf(v, wl[k * 64 + f2 + 1], a1);
        }
        a0 = fmaxf(a0, 0.f);
        a1 = fmaxf(a1, 0.f);
        int n = n0 + local;
        half2v hv = {(_Float16)a0, (_Float16)a1};
        *reinterpret_cast<half2v*>(h0h + (size_t)n * 64 + f2) = hv;
        unsigned pk = __builtin_amdgcn_cvt_pk_fp8_f32(a0, a1, 0u, false);
        *reinterpret_cast<unsigned short*>(h0q + (size_t)n * 64 + f2) =
            (unsigned short)pk;
    }
}

// ---- Kernel B: layer-1 InterAgg, 8 nodes per wave, gathers from fp8 h0q
// (L2-resident 3.2 MB), self from fp16 h0h. Writes inter1 fp16 + fp8 (both nt).
__global__ __launch_bounds__(256) void layer1_kernel(
        const int* __restrict__ adj,
        const unsigned char* __restrict__ h0q,
        const _Float16* __restrict__ h0h,
        const float* __restrict__ sw1,
        _Float16* __restrict__ i1h,
        unsigned char* __restrict__ i1q) {
    __shared__ int nb[32 * NB_STRIDE];
    __shared__ float swl[384];  // wA(192) | wB(192)
    int tid = threadIdx.x;
    int n0 = blockIdx.x * 32;
    if (tid < 96)
        reinterpret_cast<float4*>(swl)[tid] = reinterpret_cast<const float4*>(sw1)[tid];
    {
        int i0 = tid * 4;
        int m = i0 >> 5;
        int d = i0 & 31;
        int gn = n0 + m;
#pragma unroll
        for (int r = 0; r < 3; ++r) {
            int4v v = {0, 0, 0, 0};
            if (gn < N_NODES)
                v = __builtin_nontemporal_load(reinterpret_cast<const int4v*>(
                        adj + ((size_t)r * N_NODES + gn) * DEG + d));
            *reinterpret_cast<int4v*>(&nb[m * NB_STRIDE + r * 32 + d]) = v;
        }
    }
    __syncthreads();
    int w = tid >> 6, j = tid & 63;
    int m = w * 8 + (j >> 3);
    int e = j & 7;
    int n = n0 + m;
    const int* nbrow = nb + m * NB_STRIDE;
    const unsigned char* qb = h0q + 8 * e;  // octet base (8 fp8 = 8 B)
    f32x2 acc0[4] = {}, acc1[4] = {}, acc2[4] = {};
#pragma unroll 8
    for (int t = 0; t < 32; ++t) {
        uint2v d = *reinterpret_cast<const uint2v*>(qb + (size_t)((unsigned)nbrow[t] * 64u));
        acc0[0] += __builtin_amdgcn_cvt_pk_f32_fp8(d.x, false);
        acc0[1] += __builtin_amdgcn_cvt_pk_f32_fp8(d.x, true);
        acc0[2] += __builtin_amdgcn_cvt_pk_f32_fp8(d.y, false);
        acc0[3] += __builtin_amdgcn_cvt_pk_f32_fp8(d.y, true);
    }
#pragma unroll 8
    for (int t = 32; t < 64; ++t) {
        uint2v d = *reinterpret_cast<const uint2v*>(qb + (size_t)((unsigned)nbrow[t] * 64u));
        acc1[0] += __builtin_amdgcn_cvt_pk_f32_fp8(d.x, false);
        acc1[1] += __builtin_amdgcn_cvt_pk_f32_fp8(d.x, true);
        acc1[2] += __builtin_amdgcn_cvt_pk_f32_fp8(d.y, false);
        acc1[3] += __builtin_amdgcn_cvt_pk_f32_fp8(d.y, true);
    }
#pragma unroll 8
    for (int t = 64; t < 96; ++t) {
        uint2v d = *reinterpret_cast<const uint2v*>(qb + (size_t)((unsigned)nbrow[t] * 64u));
        acc2[0] += __builtin_amdgcn_cvt_pk_f32_fp8(d.x, false);
        acc2[1] += __builtin_amdgcn_cvt_pk_f32_fp8(d.x, true);
        acc2[2] += __builtin_amdgcn_cvt_pk_f32_fp8(d.y, false);
        acc2[3] += __builtin_amdgcn_cvt_pk_f32_fp8(d.y, true);
    }

    half8 sv = *reinterpret_cast<const half8*>(h0h + (size_t)n * 64 + 8 * e);
    float wA[24], wB[24];
    {
        const float4* pa = reinterpret_cast<const float4*>(swl + 24 * e);
        const float4* pb = reinterpret_cast<const float4*>(swl + 192 + 24 * e);
#pragma unroll
        for (int q = 0; q < 6; ++q) {
            float4 ta = pa[q], tb = pb[q];
            wA[4 * q] = ta.x; wA[4 * q + 1] = ta.y; wA[4 * q + 2] = ta.z; wA[4 * q + 3] = ta.w;
            wB[4 * q] = tb.x; wB[4 * q + 1] = tb.y; wB[4 * q + 2] = tb.z; wB[4 * q + 3] = tb.w;
        }
    }
    const float inv = 1.f / 32.f;
    float oa[8], ob[8];
    half8 ra, rb;
#pragma unroll
    for (int i = 0; i < 8; ++i) {
        float a0 = acc0[i >> 1][i & 1] * inv;
        float a1 = acc1[i >> 1][i & 1] * inv;
        float a2 = acc2[i >> 1][i & 1] * inv;
        float s = (float)sv[i];
        oa[i] = wA[3 * i] * a0 + wA[3 * i + 1] * a1 + wA[3 * i + 2] * a2;
        ob[i] = wB[3 * i] * (s - a0) + wB[3 * i + 1] * (s - a1) + wB[3 * i + 2] * (s - a2);
        ra[i] = (_Float16)oa[i];
        rb[i] = (_Float16)ob[i];
    }
    if (n < N_NODES) {
        __builtin_nontemporal_store(__builtin_bit_cast(int4v, ra),
            reinterpret_cast<int4v*>(i1h + (size_t)n * 128 + 8 * e));
        __builtin_nontemporal_store(__builtin_bit_cast(int4v, rb),
            reinterpret_cast<int4v*>(i1h + (size_t)n * 128 + 64 + 8 * e));
        unsigned qa0 = __builtin_amdgcn_cvt_pk_fp8_f32(oa[0], oa[1], 0u, false);
        qa0 = __builtin_amdgcn_cvt_pk_fp8_f32(oa[2], oa[3], qa0, true);
        unsigned qa1 = __builtin_amdgcn_cvt_pk_fp8_f32(oa[4], oa[5], 0u, false);
        qa1 = __builtin_amdgcn_cvt_pk_fp8_f32(oa[6], oa[7], qa1, true);
        uint2v ua = {qa0, qa1};
        __builtin_nontemporal_store(ua,
            reinterpret_cast<uint2v*>(i1q + (size_t)n * 128 + 8 * e));
        unsigned qb0 = __builtin_amdgcn_cvt_pk_fp8_f32(ob[0], ob[1], 0u, false);
        qb0 = __builtin_amdgcn_cvt_pk_fp8_f32(ob[2], ob[3], qb0, true);
        unsigned qb1 = __builtin_amdgcn_cvt_pk_fp8_f32(ob[4], ob[5], 0u, false);
        qb1 = __builtin_amdgcn_cvt_pk_fp8_f32(ob[6], ob[7], qb1, true);
        uint2v ub = {qb0, qb1};
        __builtin_nontemporal_store(ub,
            reinterpret_cast<uint2v*>(i1q + (size_t)n * 128 + 64 + 8 * e));
    }
}

// ---- Kernel C: layer-2 InterAgg (batch) + fused dense head.
// Gathers from fp8 i1q; self/head inputs from fp16 i1h/h0h.
__global__ __launch_bounds__(256) void layer2_kernel(
        const int* __restrict__ nodes,
        const int* __restrict__ adj,
        const _Float16* __restrict__ h0h,
        const _Float16* __restrict__ i1h,
        const unsigned char* __restrict__ i1q,
        const float* __restrict__ sw2,
        const float* __restrict__ w_d2,
        const float* __restrict__ b_d2,
        const float* __restrict__ w_d1,
        const float* __restrict__ b_d1,
        const float* __restrict__ prior,
        float* __restrict__ out) {
    __shared__ int nb[4][96];
    __shared__ int nid[4];
    __shared__ float swl[768];  // wA(384) | wB(384)
    int tid = threadIdx.x;
    int b0 = blockIdx.x * 4;
    if (tid < 4) nid[tid] = nodes[b0 + tid];
    if (tid >= 64 && tid < 256) {
        int q = tid - 64;
        reinterpret_cast<float4*>(swl)[q] = reinterpret_cast<const float4*>(sw2)[q];
    }
    __syncthreads();
    for (int q = tid; q < 384; q += 256) {
        int local = q / 96, idx = q - local * 96;
        int r = idx >> 5, d = idx & 31;
        nb[local][idx] = __builtin_nontemporal_load(
            adj + ((size_t)r * N_NODES + nid[local]) * DEG + d);
    }
    __syncthreads();
    int local = tid >> 6, j = tid & 63;
    int bb = b0 + local;
    int n = nid[local];
    int g = j >> 4, e = j & 15;
    int idxs[24];
#pragma unroll
    for (int t = 0; t < 24; ++t) idxs[t] = nb[local][t * 4 + g];
    const unsigned char* qbase = i1q + 8 * e;
    f32x2 acc0[4] = {}, acc1[4] = {}, acc2[4] = {};
#pragma unroll
    for (int t = 0; t < 8; ++t) {
        uint2v d = *reinterpret_cast<const uint2v*>(qbase + (size_t)((unsigned)idxs[t] * 128u));
        acc0[0] += __builtin_amdgcn_cvt_pk_f32_fp8(d.x, false);
        acc0[1] += __builtin_amdgcn_cvt_pk_f32_fp8(d.x, true);
        acc0[2] += __builtin_amdgcn_cvt_pk_f32_fp8(d.y, false);
        acc0[3] += __builtin_amdgcn_cvt_pk_f32_fp8(d.y, true);
    }
#pragma unroll
    for (int t = 8; t < 16; ++t) {
        uint2v d = *reinterpret_cast<const uint2v*>(qbase + (size_t)((unsigned)idxs[t] * 128u));
        acc1[0] += __builtin_amdgcn_cvt_pk_f32_fp8(d.x, false);
        acc1[1] += __builtin_amdgcn_cvt_pk_f32_fp8(d.x, true);
        acc1[2] += __builtin_amdgcn_cvt_pk_f32_fp8(d.y, false);
        acc1[3] += __builtin_amdgcn_cvt_pk_f32_fp8(d.y, true);
    }
#pragma unroll
    for (int t = 16; t < 24; ++t) {
        uint2v d = *reinterpret_cast<const uint2v*>(qbase + (size_t)((unsigned)idxs[t] * 128u));
        acc2[0] += __builtin_amdgcn_cvt_pk_f32_fp8(d.x, false);
        acc2[1] += __builtin_amdgcn_cvt_pk_f32_fp8(d.x, true);
        acc2[2] += __builtin_amdgcn_cvt_pk_f32_fp8(d.y, false);
        acc2[3] += __builtin_amdgcn_cvt_pk_f32_fp8(d.y, true);
    }
#pragma unroll
    for (int mm = 16; mm <= 32; mm <<= 1) {
#pragma unroll
        for (int q = 0; q < 4; ++q) {
            acc0[q] += shfl_xor_f2(acc0[q], mm);
            acc1[q] += shfl_xor_f2(acc1[q], mm);
            acc2[q] += shfl_xor_f2(acc2[q], mm);
        }
    }
    const float inv = 1.f / 32.f;
    float p0 = 0.f, p1 = 0.f;
    if (g == 0) {
        half8 sv = *reinterpret_cast<const half8*>(i1h + (size_t)n * 128 + 8 * e);
        const float* wa = swl + 24 * e;
        const float* wb = swl + 384 + 24 * e;
#pragma unroll
        for (int i = 0; i < 8; ++i) {
            int f = 8 * e + i;
            float a0 = acc0[i >> 1][i & 1] * inv;
            float a1 = acc1[i >> 1][i & 1] * inv;
            float a2 = acc2[i >> 1][i & 1] * inv;
            float s = (float)sv[i];
            float i2a = wa[3 * i] * a0 + wa[3 * i + 1] * a1 + wa[3 * i + 2] * a2;
            float i2b = wb[3 * i] * (s - a0) + wb[3 * i + 1] * (s - a1) +
                        wb[3 * i + 2] * (s - a2);
            p0 += i2a * w_d2[(192 + f) * 2 + 0] + i2b * w_d2[(320 + f) * 2 + 0];
            p1 += i2a * w_d2[(192 + f) * 2 + 1] + i2b * w_d2[(320 + f) * 2 + 1];
        }
    } else if (g == 1) {
#pragma unroll
        for (int i = 0; i < 4; ++i) {
            int f = 4 * e + i;
            float s = (float)h0h[(size_t)n * 64 + f];
            p0 += s * w_d2[f * 2 + 0];
            p1 += s * w_d2[f * 2 + 1];
        }
    } else if (g == 2) {
        half8 sv = *reinterpret_cast<const half8*>(i1h + (size_t)n * 128 + 8 * e);
#pragma unroll
        for (int i = 0; i < 8; ++i) {
            int f = 8 * e + i;
            float s = (float)sv[i];
            p0 += s * w_d2[(64 + f) * 2 + 0];
            p1 += s * w_d2[(64 + f) * 2 + 1];
        }
    }
#pragma unroll
    for (int mm = 1; mm <= 32; mm <<= 1) {
        p0 += __shfl_xor(p0, mm, 64);
        p1 += __shfl_xor(p1, mm, 64);
    }
    if (j == 0) {
        float x0 = p0 + b_d2[0], x1 = p1 + b_d2[1];
        x0 = x0 > 0.f ? x0 : 0.3f * x0;
        x1 = x1 > 0.f ? x1 : 0.3f * x1;
        x0 += __logf(prior[0]);
        x1 += __logf(prior[1]);
        float z = x0 * w_d1[0] + x1 * w_d1[1] + b_d1[0];
        out[bb] = 1.f / (1.f + __expf(-z));
    }
}

extern "C" void kernel_launch(void* const* d_in, const int* in_sizes, int n_in,
                              void* d_out, int out_size, void* d_ws, size_t ws_size,
                              hipStream_t stream) {
    const int*   nodes  = (const int*)d_in[0];
    const float* feat   = (const float*)d_in[1];
    const int*   adj    = (const int*)d_in[2];
    const float* prior  = (const float*)d_in[3];
    const float* w_mlp  = (const float*)d_in[4];
    const float* b_mlp  = (const float*)d_in[5];
    const float* alpha1 = (const float*)d_in[6];
    const float* alpha2 = (const float*)d_in[7];
    const float* w_d2   = (const float*)d_in[8];
    const float* b_d2   = (const float*)d_in[9];
    const float* w_d1   = (const float*)d_in[10];
    const float* b_d1   = (const float*)d_in[11];
    float* out = (float*)d_out;

    // ws: sw1(384f) | sw2(768f) | pad->8192 | h0h fp16 N*64 (6.4MB) |
    //     i1h fp16 N*128 (12.8MB) | h0q fp8 N*64 (3.2MB) | i1q fp8 N*128 (6.4MB)
    float* sw1 = (float*)d_ws;
    float* sw2 = sw1 + 128 * 3;
    _Float16* h0h = (_Float16*)((char*)d_ws + 8192);
    _Float16* i1h = h0h + (size_t)N_NODES * 64;
    unsigned char* h0q = (unsigned char*)(i1h + (size_t)N_NODES * 128);
    unsigned char* i1q = h0q + (size_t)N_NODES * 64;

    mlp_kernel<<<2048, 256, 0, stream>>>(feat, w_mlp, b_mlp, alpha1, alpha2,
                                         sw1, sw2, h0h, h0q);
    layer1_kernel<<<(N_NODES + 31) / 32, 256, 0, stream>>>(adj, h0q, h0h, sw1,
                                                           i1h, i1q);
    layer2_kernel<<<BATCH / 4, 256, 0, stream>>>(nodes, adj, h0h, i1h, i1q, sw2,
                                                 w_d2, b_d2, w_d1, b_d1, prior, out);
}